// Round 4
// baseline (3298.605 us; speedup 1.0000x reference)
//
#include <hip/hip_runtime.h>
#include <cstdint>
#include <cstddef>

#define B_ 16
#define N_ 2048
#define L_ 12
#define C_ 32
#define KTOP 1638
#define SCALE 0.17677669529663687f   // 1/sqrt(32)

// Kernel 1: xsumT[b][c][n] = sum_l x[b][n][l][c]   (B,C,N layout, 4 MB in d_ws)
__global__ __launch_bounds__(256) void xsum_kernel(const float* __restrict__ x,
                                                   float* __restrict__ xsumT) {
  const int b = blockIdx.y;
  const int n0 = blockIdx.x * 64;
  __shared__ float tile[64][33];  // +1 pad: conflict-free transpose
  const int c = threadIdx.x & 31;
  const int nr = threadIdx.x >> 5;  // 0..7
#pragma unroll
  for (int i = 0; i < 8; ++i) {
    const int n = n0 + i * 8 + nr;
    const float* px = x + ((size_t)(b * N_ + n) * L_) * C_ + c;
    float s = 0.f;
#pragma unroll
    for (int l = 0; l < L_; ++l) s += px[l * C_];
    tile[i * 8 + nr][c] = s;
  }
  __syncthreads();
  const int n2 = threadIdx.x & 63;
  const int c2b = threadIdx.x >> 6;  // 0..3
#pragma unroll
  for (int i = 0; i < 8; ++i) {
    const int c2 = c2b + i * 4;
    xsumT[((size_t)b * C_ + c2) * N_ + n0 + n2] = tile[n2][c2];
  }
}

__device__ __forceinline__ unsigned short f32_to_bf16_rne(float v) {
  unsigned u = __float_as_uint(v);
  u += 0x7FFFu + ((u >> 16) & 1u);
  return (unsigned short)(u >> 16);
}

// Kernel 2: one block = 8 rows of one batch, 512 threads (8 waves).
// bf16 adjbuf -> 34 KB LDS -> 4 blocks/CU; launch_bounds(512,8) so the
// waves-per-EU attribute doesn't clamp occupancy below 8 waves/SIMD
// (R1-R3 evidence: occupancy tracked the 2nd arg exactly: 2->23%, 4->44%).
__global__ __launch_bounds__(512, 8) void adj_kernel(
    const float* __restrict__ xsumT, const float* __restrict__ mem,
    const float* __restrict__ fc_w, const float* __restrict__ fc_b,
    float* __restrict__ out) {
  __shared__ unsigned short adjbuf[8][2048];  // 32 KB (bf16 bits)
  __shared__ float xrow[8][32];
  __shared__ float red[8][16];

  const int tid = threadIdx.x;
  const int wid = tid >> 6, lane = tid & 63;
  const int b = blockIdx.y;
  const int n0 = blockIdx.x * 8;

  if (tid < 256) {
    const int r = tid >> 5, c = tid & 31;
    xrow[r][c] = xsumT[((size_t)b * C_ + c) * N_ + n0 + r];
  }
  __syncthreads();

  // ---- Phase A: dot products. Thread owns columns m = tid*4 .. tid*4+3 ----
  float acc1[8][4], acc2[8][4];
#pragma unroll
  for (int r = 0; r < 8; ++r)
#pragma unroll
    for (int j = 0; j < 4; ++j) { acc1[r][j] = 0.f; acc2[r][j] = 0.f; }

  const float* mp = mem + tid * 4;
  const float* xp = xsumT + (size_t)b * C_ * N_ + tid * 4;

#pragma unroll 4
  for (int c = 0; c < C_; ++c) {
    const float4 mt = *(const float4*)(mp + (size_t)c * N_);
    const float4 xt = *(const float4*)(xp + (size_t)c * N_);
    const float m4[4] = {mt.x, mt.y, mt.z, mt.w};
    const float x4[4] = {xt.x, xt.y, xt.z, xt.w};
#pragma unroll
    for (int r = 0; r < 8; ++r) {
      const float xv = xrow[r][c];
#pragma unroll
      for (int j = 0; j < 4; ++j) {
        acc1[r][j] = fmaf(xv, m4[j], acc1[r][j]);
        acc2[r][j] = fmaf(xv, x4[j], acc2[r][j]);
      }
    }
  }

  // relu(e*scale)
#pragma unroll
  for (int r = 0; r < 8; ++r)
#pragma unroll
    for (int j = 0; j < 4; ++j) {
      acc1[r][j] = fmaxf(acc1[r][j] * SCALE, 0.f);
      acc2[r][j] = fmaxf(acc2[r][j] * SCALE, 0.f);
    }

  // ---- block max over 16 channels (rows 0..7 for e1, 8..15 for e2) ----
  float st[16];
#pragma unroll
  for (int r = 0; r < 8; ++r) {
    float a = acc1[r][0], b2 = acc2[r][0];
#pragma unroll
    for (int j = 1; j < 4; ++j) { a = fmaxf(a, acc1[r][j]); b2 = fmaxf(b2, acc2[r][j]); }
    st[r] = a; st[8 + r] = b2;
  }
#pragma unroll
  for (int d = 1; d < 64; d <<= 1)
#pragma unroll
    for (int ch = 0; ch < 16; ++ch) st[ch] = fmaxf(st[ch], __shfl_xor(st[ch], d));
  if (lane == 0) {
#pragma unroll
    for (int ch = 0; ch < 16; ++ch) red[wid][ch] = st[ch];
  }
  __syncthreads();
  float mx[16];
#pragma unroll
  for (int ch = 0; ch < 16; ++ch) {
    float v = red[0][ch];
#pragma unroll
    for (int w = 1; w < 8; ++w) v = fmaxf(v, red[w][ch]);
    mx[ch] = v;
  }
  __syncthreads();  // red about to be reused

  // ---- exp + block sum ----
#pragma unroll
  for (int r = 0; r < 8; ++r) {
    float s1 = 0.f, s2 = 0.f;
#pragma unroll
    for (int j = 0; j < 4; ++j) {
      acc1[r][j] = __expf(acc1[r][j] - mx[r]);
      acc2[r][j] = __expf(acc2[r][j] - mx[8 + r]);
      s1 += acc1[r][j]; s2 += acc2[r][j];
    }
    st[r] = s1; st[8 + r] = s2;
  }
#pragma unroll
  for (int d = 1; d < 64; d <<= 1)
#pragma unroll
    for (int ch = 0; ch < 16; ++ch) st[ch] += __shfl_xor(st[ch], d);
  if (lane == 0) {
#pragma unroll
    for (int ch = 0; ch < 16; ++ch) red[wid][ch] = st[ch];
  }
  __syncthreads();
  float sm[16];
#pragma unroll
  for (int ch = 0; ch < 16; ++ch) {
    float v = 0.f;
#pragma unroll
    for (int w = 0; w < 8; ++w) v += red[w][ch];
    sm[ch] = v;
  }

  // ---- adj = w0*a1 + w1*a2 + b -> bf16 -> LDS ----
  const float w0 = fc_w[0], w1 = fc_w[1], bb = fc_b[0];
#pragma unroll
  for (int r = 0; r < 8; ++r) {
    const float i1 = w0 / sm[r];
    const float i2 = w1 / sm[8 + r];
    ushort4 pk;
    pk.x = f32_to_bf16_rne(fmaf(acc1[r][0], i1, fmaf(acc2[r][0], i2, bb)));
    pk.y = f32_to_bf16_rne(fmaf(acc1[r][1], i1, fmaf(acc2[r][1], i2, bb)));
    pk.z = f32_to_bf16_rne(fmaf(acc1[r][2], i1, fmaf(acc2[r][2], i2, bb)));
    pk.w = f32_to_bf16_rne(fmaf(acc1[r][3], i1, fmaf(acc2[r][3], i2, bb)));
    *(ushort4*)&adjbuf[r][tid * 4] = pk;
  }
  __syncthreads();

  // ---- Phase B: wave wid owns row wid. 16-bit threshold search + softmax ----
  {
    const int r = wid;
    unsigned short bits[32];
#pragma unroll
    for (int k = 0; k < 8; ++k) {
      const ushort4 q = *(const ushort4*)&adjbuf[r][lane * 4 + (k << 8)];
      bits[k * 4 + 0] = q.x; bits[k * 4 + 1] = q.y;
      bits[k * 4 + 2] = q.z; bits[k * 4 + 3] = q.w;
    }
    unsigned ku[32];
#pragma unroll
    for (int i = 0; i < 32; ++i) {
      const unsigned v = bits[i];
      ku[i] = v ^ (0x8000u + (v >> 15) * 0x7FFFu);  // sortable u16
    }
    unsigned mn = ku[0], mxu = ku[0];
#pragma unroll
    for (int i = 1; i < 32; ++i) { mn = min(mn, ku[i]); mxu = max(mxu, ku[i]); }
#pragma unroll
    for (int d = 1; d < 64; d <<= 1) {
      mn  = min(mn,  (unsigned)__shfl_xor((int)mn,  d));
      mxu = max(mxu, (unsigned)__shfl_xor((int)mxu, d));
    }
    unsigned lo = mn, hi = mxu;
#pragma unroll 1
    for (int it = 0; it < 16; ++it) {
      if (lo >= hi) break;
      const unsigned mid = (lo + hi + 1u) >> 1;
      int cnt = 0;
#pragma unroll
      for (int i = 0; i < 32; ++i) cnt += (int)__popcll(__ballot(ku[i] >= mid));
      if (cnt >= KTOP) lo = mid; else hi = mid - 1;
    }
    // mask (zero dropped entries), final softmax
    float a[32];
    float m3 = 0.f;
#pragma unroll
    for (int i = 0; i < 32; ++i) {
      const float v = __uint_as_float(((unsigned)bits[i]) << 16);
      const float l = (ku[i] >= lo) ? v : 0.f;
      a[i] = l;
      m3 = fmaxf(m3, l);
    }
#pragma unroll
    for (int d = 1; d < 64; d <<= 1) m3 = fmaxf(m3, __shfl_xor(m3, d));
    float s = 0.f;
#pragma unroll
    for (int i = 0; i < 32; ++i) { a[i] = __expf(a[i] - m3); s += a[i]; }
#pragma unroll
    for (int d = 1; d < 64; d <<= 1) s += __shfl_xor(s, d);
    const float inv = 1.f / s;
    float* op = out + ((size_t)b * N_ + n0 + r) * N_;
#pragma unroll
    for (int k = 0; k < 8; ++k) {
      float4 o;
      o.x = a[k * 4 + 0] * inv; o.y = a[k * 4 + 1] * inv;
      o.z = a[k * 4 + 2] * inv; o.w = a[k * 4 + 3] * inv;
      *(float4*)(op + lane * 4 + (k << 8)) = o;
    }
  }
}

extern "C" void kernel_launch(void* const* d_in, const int* in_sizes, int n_in,
                              void* d_out, int out_size, void* d_ws, size_t ws_size,
                              hipStream_t stream) {
  const float* x   = (const float*)d_in[0];
  const float* mem = (const float*)d_in[1];
  const float* fcw = (const float*)d_in[2];
  const float* fcb = (const float*)d_in[3];
  float* out = (float*)d_out;
  float* xsumT = (float*)d_ws;  // B_*C_*N_ floats = 4 MB

  dim3 g1(N_ / 64, B_);
  xsum_kernel<<<g1, 256, 0, stream>>>(x, xsumT);
  dim3 g2(N_ / 8, B_);
  adj_kernel<<<g2, 512, 0, stream>>>(xsumT, mem, fcw, fcb, out);
}

// Round 5
// 239.063 us; speedup vs baseline: 13.7981x; 13.7981x over previous
//
#include <hip/hip_runtime.h>
#include <cstdint>
#include <cstddef>

#define B_ 16
#define N_ 2048
#define L_ 12
#define C_ 32
#define KTOP 1638
#define SCALE 0.17677669529663687f   // 1/sqrt(32)
#define LOG2E 1.44269504088896f

typedef __attribute__((ext_vector_type(8))) short short8v;
typedef __attribute__((ext_vector_type(4))) float f32x4;

__device__ __forceinline__ unsigned short bf16_rne(float v) {
  unsigned u = __float_as_uint(v);
  u += 0x7FFFu + ((u >> 16) & 1u);
  return (unsigned short)(u >> 16);
}

// Kernel 1: xsum = sum_l x, split into bf16 hi/lo arrays, layout [b][n][c]
// (row-major in c so MFMA A/B fragments load as one contiguous 16B dwordx4).
__global__ __launch_bounds__(256) void prep_kernel(const float* __restrict__ x,
                                                   unsigned short* __restrict__ xsH,
                                                   unsigned short* __restrict__ xsL) {
  const int b = blockIdx.y, n0 = blockIdx.x * 64;
  const int c = threadIdx.x & 31, nr = threadIdx.x >> 5;
#pragma unroll
  for (int i = 0; i < 8; ++i) {
    const int n = n0 + i * 8 + nr;
    const float* px = x + ((size_t)(b * N_ + n) * L_) * C_ + c;
    float s = 0.f;
#pragma unroll
    for (int l = 0; l < L_; ++l) s += px[l * C_];
    const unsigned short h = bf16_rne(s);
    const float hf = __uint_as_float((unsigned)h << 16);
    const unsigned short lo = bf16_rne(s - hf);
    const size_t o = (size_t)(b * N_ + n) * C_ + c;
    xsH[o] = h;
    xsL[o] = lo;
  }
}

// Kernel 2: one block = 8 rows of one batch, 512 threads (8 waves).
// Phase A: MFMA 16x16x32 (rows padded 8->16). e1 = xs_hi x mem_bf16;
// e2 = hi*hi + hi*lo + lo*hi (split bf16 ~ f32 precision).
// Max-free softmaxes: p1 = e^l1 (l1 small), p2 = e^(l2-80) (f32 range ok).
// p1,p2 packed bf16-pair per u32 into LDS; phase B: adj reconstruct +
// 16-bit threshold search + final softmax (R3-proven).
__global__ __launch_bounds__(512, 4) void adj_kernel(
    const unsigned short* __restrict__ xsH, const unsigned short* __restrict__ xsL,
    const float* __restrict__ mem, const float* __restrict__ fc_w,
    const float* __restrict__ fc_b, float* __restrict__ out) {
  __shared__ unsigned pbuf[8][2048];      // 64 KB: (bf16(p2)<<16)|bf16(p1)
  __shared__ float red1[8][8], red2[8][8];

  const int tid = threadIdx.x, wid = tid >> 6, lane = tid & 63;
  const int l15 = lane & 15, g = lane >> 4;
  const int b = blockIdx.y, n0 = blockIdx.x * 8;

  // A fragments: row = l15 (rows 8-15 are padding -> duplicate rows 0-7)
  const size_t arow = (size_t)(b * N_ + n0 + (l15 & 7)) * C_ + g * 8;
  const short8v hiA = *(const short8v*)(xsH + arow);
  const short8v loA = *(const short8v*)(xsL + arow);

  const f32x4 zero = {0.f, 0.f, 0.f, 0.f};
  float s1[4] = {0.f, 0.f, 0.f, 0.f}, s2[4] = {0.f, 0.f, 0.f, 0.f};
  const float K = SCALE * LOG2E;
  const float C2 = -80.f * LOG2E;
  const size_t xbase = (size_t)b * N_ * C_;

  for (int t = 0; t < 16; ++t) {
    const int m = wid * 256 + t * 16 + l15;   // output column
    const size_t brow = xbase + (size_t)m * C_ + g * 8;
    const short8v hiB = *(const short8v*)(xsH + brow);
    const short8v loB = *(const short8v*)(xsL + brow);
    // e1 B-fragment from mem (f32 [c][m], strided in c) -> bf16
    const float* mp = mem + (size_t)(g * 8) * N_ + m;
    short8v memB;
#pragma unroll
    for (int e = 0; e < 8; ++e) memB[e] = (short)bf16_rne(mp[(size_t)e * N_]);

    f32x4 acc1 = __builtin_amdgcn_mfma_f32_16x16x32_bf16(hiA, memB, zero, 0, 0, 0);
    f32x4 acc2 = __builtin_amdgcn_mfma_f32_16x16x32_bf16(hiA, hiB, zero, 0, 0, 0);
    acc2 = __builtin_amdgcn_mfma_f32_16x16x32_bf16(hiA, loB, acc2, 0, 0, 0);
    acc2 = __builtin_amdgcn_mfma_f32_16x16x32_bf16(loA, hiB, acc2, 0, 0, 0);

    if (lane < 32) {  // C rows 0-7 live in lanes 0-31 (row = g*4+j)
#pragma unroll
      for (int j = 0; j < 4; ++j) {
        const float p1 = exp2f(fmaxf(acc1[j], 0.f) * K);
        const float t2 = fminf(fmaf(fmaxf(acc2[j], 0.f), K, C2), 127.f);
        const float p2 = exp2f(t2);
        s1[j] += p1;
        s2[j] += p2;
        pbuf[g * 4 + j][m] = ((unsigned)bf16_rne(p2) << 16) | (unsigned)bf16_rne(p1);
      }
    }
  }

  // row-sum: reduce over the 16-lane column group, then across 8 waves
#pragma unroll
  for (int d = 1; d < 16; d <<= 1) {
#pragma unroll
    for (int j = 0; j < 4; ++j) {
      s1[j] += __shfl_xor(s1[j], d);
      s2[j] += __shfl_xor(s2[j], d);
    }
  }
  if (l15 == 0 && g < 2) {
#pragma unroll
    for (int j = 0; j < 4; ++j) {
      red1[wid][g * 4 + j] = s1[j];
      red2[wid][g * 4 + j] = s2[j];
    }
  }
  __syncthreads();

  // ---- Phase B: wave wid owns row wid ----
  {
    const int r = wid;
    float S1 = 0.f, S2 = 0.f;
#pragma unroll
    for (int w = 0; w < 8; ++w) { S1 += red1[w][r]; S2 += red2[w][r]; }
    const float w0 = fc_w[0], w1 = fc_w[1], bb = fc_b[0];
    const float i1 = w0 / S1, i2 = w1 / S2;

    unsigned short bits[32];
#pragma unroll
    for (int k = 0; k < 8; ++k) {
      const uint4 q = *(const uint4*)&pbuf[r][lane * 4 + (k << 8)];
      const unsigned qq[4] = {q.x, q.y, q.z, q.w};
#pragma unroll
      for (int c4 = 0; c4 < 4; ++c4) {
        const float p1 = __uint_as_float(qq[c4] << 16);
        const float p2 = __uint_as_float(qq[c4] & 0xFFFF0000u);
        const float adj = fmaf(p2, i2, fmaf(p1, i1, bb));
        bits[k * 4 + c4] = bf16_rne(adj);
      }
    }
    unsigned ku[32];
#pragma unroll
    for (int i = 0; i < 32; ++i) {
      const unsigned v = bits[i];
      ku[i] = v ^ (0x8000u + (v >> 15) * 0x7FFFu);  // sortable u16
    }
    unsigned mn = ku[0], mxu = ku[0];
#pragma unroll
    for (int i = 1; i < 32; ++i) { mn = min(mn, ku[i]); mxu = max(mxu, ku[i]); }
#pragma unroll
    for (int d = 1; d < 64; d <<= 1) {
      mn  = min(mn,  (unsigned)__shfl_xor((int)mn,  d));
      mxu = max(mxu, (unsigned)__shfl_xor((int)mxu, d));
    }
    unsigned lo = mn, hi = mxu;
#pragma unroll 1
    for (int it = 0; it < 16; ++it) {
      if (lo >= hi) break;
      const unsigned mid = (lo + hi + 1u) >> 1;
      int cnt = 0;
#pragma unroll
      for (int i = 0; i < 32; ++i) cnt += (int)__popcll(__ballot(ku[i] >= mid));
      if (cnt >= KTOP) lo = mid; else hi = mid - 1;
    }
    float a[32];
    float m3 = 0.f;
#pragma unroll
    for (int i = 0; i < 32; ++i) {
      const float v = __uint_as_float(((unsigned)bits[i]) << 16);
      const float l = (ku[i] >= lo) ? v : 0.f;
      a[i] = l;
      m3 = fmaxf(m3, l);
    }
#pragma unroll
    for (int d = 1; d < 64; d <<= 1) m3 = fmaxf(m3, __shfl_xor(m3, d));
    float s = 0.f;
#pragma unroll
    for (int i = 0; i < 32; ++i) { a[i] = __expf(a[i] - m3); s += a[i]; }
#pragma unroll
    for (int d = 1; d < 64; d <<= 1) s += __shfl_xor(s, d);
    const float inv = 1.f / s;
    float* op = out + ((size_t)b * N_ + n0 + r) * N_;
#pragma unroll
    for (int k = 0; k < 8; ++k) {
      float4 o;
      o.x = a[k * 4 + 0] * inv; o.y = a[k * 4 + 1] * inv;
      o.z = a[k * 4 + 2] * inv; o.w = a[k * 4 + 3] * inv;
      *(float4*)(op + lane * 4 + (k << 8)) = o;
    }
  }
}

extern "C" void kernel_launch(void* const* d_in, const int* in_sizes, int n_in,
                              void* d_out, int out_size, void* d_ws, size_t ws_size,
                              hipStream_t stream) {
  const float* x   = (const float*)d_in[0];
  const float* mem = (const float*)d_in[1];
  const float* fcw = (const float*)d_in[2];
  const float* fcb = (const float*)d_in[3];
  float* out = (float*)d_out;
  unsigned short* xsH = (unsigned short*)d_ws;              // 2 MB
  unsigned short* xsL = xsH + (size_t)B_ * N_ * C_;         // 2 MB (total 4 MB, proven safe)

  dim3 g1(N_ / 64, B_);
  prep_kernel<<<g1, 256, 0, stream>>>(x, xsH, xsL);
  dim3 g2(N_ / 8, B_);
  adj_kernel<<<g2, 512, 0, stream>>>(xsH, xsL, mem, fcw, fcb, out);
}

// Round 6
// 184.277 us; speedup vs baseline: 17.9002x; 1.2973x over previous
//
#include <hip/hip_runtime.h>
#include <hip/hip_bf16.h>
#include <cstdint>
#include <cstddef>

#define B_ 16
#define N_ 2048
#define L_ 12
#define C_ 32
#define KTOP 1638
#define SCALE 0.17677669529663687f   // 1/sqrt(32)
#define LOG2E 1.44269504088896f

typedef __attribute__((ext_vector_type(8))) short short8v;
typedef __attribute__((ext_vector_type(4))) float f32x4;

__device__ __forceinline__ unsigned short bf16_rne(float v) {
  unsigned u = __float_as_uint(v);
  u += 0x7FFFu + ((u >> 16) & 1u);
  return (unsigned short)(u >> 16);
}

// Kernel 1: xsum split into bf16 hi/lo, layout [b][n][c]; blocks with b==0
// also convert mem (f32 [c][m]) -> bf16 memT [m][c] (batch-invariant, once).
__global__ __launch_bounds__(256) void prep_kernel(const float* __restrict__ x,
                                                   const float* __restrict__ mem,
                                                   unsigned short* __restrict__ xsH,
                                                   unsigned short* __restrict__ xsL,
                                                   unsigned short* __restrict__ memT) {
  const int b = blockIdx.y, n0 = blockIdx.x * 64;
  const int c = threadIdx.x & 31, nr = threadIdx.x >> 5;
#pragma unroll
  for (int i = 0; i < 8; ++i) {
    const int n = n0 + i * 8 + nr;
    const float* px = x + ((size_t)(b * N_ + n) * L_) * C_ + c;
    float s = 0.f;
#pragma unroll
    for (int l = 0; l < L_; ++l) s += px[l * C_];
    const unsigned short h = bf16_rne(s);
    const float hf = __uint_as_float((unsigned)h << 16);
    const unsigned short lo = bf16_rne(s - hf);
    const size_t o = (size_t)(b * N_ + n) * C_ + c;
    xsH[o] = h;
    xsL[o] = lo;
  }
  if (b == 0) {
#pragma unroll
    for (int i = 0; i < 8; ++i) {
      const int idx = i * 256 + threadIdx.x;
      const int ml = idx >> 5, cc = idx & 31;
      memT[(size_t)(n0 + ml) * C_ + cc] = bf16_rne(mem[(size_t)cc * N_ + n0 + ml]);
    }
  }
}

// Kernel 2: one block = 8 rows of one batch, 512 threads (8 waves).
// Phase A: MFMA 16x16x32, rows padded 8->16 (C rows 8-15 duplicate 0-7).
// Lane groups g=0,1 process j=0,1; g=2,3 process j=2,3 -> all 64 lanes do
// exp/pack (was half-wave). Max-free softmaxes; p1,p2 cvt_pk'd into pbuf.
// Phase B: adj reconstruct + 16-bit threshold search + final softmax.
__global__ __launch_bounds__(512, 4) void adj_kernel(
    const unsigned short* __restrict__ xsH, const unsigned short* __restrict__ xsL,
    const unsigned short* __restrict__ memT, const float* __restrict__ fc_w,
    const float* __restrict__ fc_b, float* __restrict__ out) {
  __shared__ unsigned pbuf[8][2049];      // +1 pad: 4 rows/slot -> 4 banks
  __shared__ float red1[8][8], red2[8][8];

  const int tid = threadIdx.x, wid = tid >> 6, lane = tid & 63;
  const int l15 = lane & 15, g = lane >> 4;
  const int b = blockIdx.y, n0 = blockIdx.x * 8;

  // A fragments: row = l15 (rows 8-15 duplicate rows 0-7)
  const size_t arow = (size_t)(b * N_ + n0 + (l15 & 7)) * C_ + g * 8;
  const short8v hiA = *(const short8v*)(xsH + arow);
  const short8v loA = *(const short8v*)(xsL + arow);

  const f32x4 zero = {0.f, 0.f, 0.f, 0.f};
  float s1[2] = {0.f, 0.f}, s2[2] = {0.f, 0.f};
  const float K = SCALE * LOG2E;
  const float C2 = -80.f * LOG2E;
  const size_t xbase = (size_t)b * N_ * C_;
  const int g8 = g * 8;
  const bool hih = (g & 2) != 0;
  const int rbase = (g & 1) * 4 + (g & 2);   // row for s=0; s=1 -> rbase+1
  unsigned* pw = &pbuf[0][0] + rbase * 2049;

#pragma unroll 2
  for (int t = 0; t < 16; ++t) {
    const int m = wid * 256 + t * 16 + l15;   // output column
    const size_t brow = xbase + (size_t)m * C_ + g8;
    const short8v hiB = *(const short8v*)(xsH + brow);
    const short8v loB = *(const short8v*)(xsL + brow);
    const short8v mB  = *(const short8v*)(memT + (size_t)m * C_ + g8);

    f32x4 acc1 = __builtin_amdgcn_mfma_f32_16x16x32_bf16(hiA, mB, zero, 0, 0, 0);
    f32x4 acc2 = __builtin_amdgcn_mfma_f32_16x16x32_bf16(hiA, hiB, zero, 0, 0, 0);
    acc2 = __builtin_amdgcn_mfma_f32_16x16x32_bf16(hiA, loB, acc2, 0, 0, 0);
    acc2 = __builtin_amdgcn_mfma_f32_16x16x32_bf16(loA, hiB, acc2, 0, 0, 0);

#pragma unroll
    for (int s = 0; s < 2; ++s) {
      const float a1v = hih ? acc1[2 + s] : acc1[s];
      const float a2v = hih ? acc2[2 + s] : acc2[s];
      const float p1 = exp2f(fmaxf(a1v, 0.f) * K);
      const float p2 = exp2f(fminf(fmaf(fmaxf(a2v, 0.f), K, C2), 127.f));
      s1[s] += p1;
      s2[s] += p2;
      union { __hip_bfloat162 h2; unsigned u; } pk;
      pk.h2 = __float22bfloat162_rn(float2{p1, p2});  // lo=bf16(p1), hi=bf16(p2)
      pw[s * 2049 + m] = pk.u;
    }
  }

  // reduce sums over the 16-lane column group, deposit per (wave,row)
#pragma unroll
  for (int d = 1; d < 16; d <<= 1) {
#pragma unroll
    for (int s = 0; s < 2; ++s) {
      s1[s] += __shfl_xor(s1[s], d);
      s2[s] += __shfl_xor(s2[s], d);
    }
  }
  if (l15 == 0) {
#pragma unroll
    for (int s = 0; s < 2; ++s) {
      red1[wid][rbase + s] = s1[s];
      red2[wid][rbase + s] = s2[s];
    }
  }
  __syncthreads();

  // ---- Phase B: wave wid owns row wid ----
  {
    const int r = wid;
    float S1 = 0.f, S2 = 0.f;
#pragma unroll
    for (int w = 0; w < 8; ++w) { S1 += red1[w][r]; S2 += red2[w][r]; }
    const float w0 = fc_w[0], w1 = fc_w[1], bb = fc_b[0];
    const float i1 = w0 / S1, i2 = w1 / S2;
    const unsigned* prow = &pbuf[0][0] + r * 2049;

    unsigned short bits[32];
#pragma unroll
    for (int i = 0; i < 32; ++i) {
      const unsigned q = prow[lane + (i << 6)];       // stride-64: 2-way (free)
      const float p1 = __uint_as_float(q << 16);
      const float p2 = __uint_as_float(q & 0xFFFF0000u);
      bits[i] = bf16_rne(fmaf(p2, i2, fmaf(p1, i1, bb)));
    }
    unsigned ku[32];
#pragma unroll
    for (int i = 0; i < 32; ++i) {
      const unsigned v = bits[i];
      ku[i] = v ^ (0x8000u + (v >> 15) * 0x7FFFu);  // sortable u16
    }
    unsigned mn = ku[0], mxu = ku[0];
#pragma unroll
    for (int i = 1; i < 32; ++i) { mn = min(mn, ku[i]); mxu = max(mxu, ku[i]); }
#pragma unroll
    for (int d = 1; d < 64; d <<= 1) {
      mn  = min(mn,  (unsigned)__shfl_xor((int)mn,  d));
      mxu = max(mxu, (unsigned)__shfl_xor((int)mxu, d));
    }
    unsigned lo = mn, hi = mxu;
#pragma unroll 1
    for (int it = 0; it < 16; ++it) {
      if (lo >= hi) break;
      const unsigned mid = (lo + hi + 1u) >> 1;
      int cnt = 0;
#pragma unroll
      for (int i = 0; i < 32; ++i) cnt += (int)__popcll(__ballot(ku[i] >= mid));
      if (cnt >= KTOP) lo = mid; else hi = mid - 1;
    }
    float a[32];
    float m3 = 0.f;
#pragma unroll
    for (int i = 0; i < 32; ++i) {
      const float v = __uint_as_float(((unsigned)bits[i]) << 16);
      const float l = (ku[i] >= lo) ? v : 0.f;
      a[i] = l;
      m3 = fmaxf(m3, l);
    }
#pragma unroll
    for (int d = 1; d < 64; d <<= 1) m3 = fmaxf(m3, __shfl_xor(m3, d));
    float s = 0.f;
#pragma unroll
    for (int i = 0; i < 32; ++i) { a[i] = __expf(a[i] - m3); s += a[i]; }
#pragma unroll
    for (int d = 1; d < 64; d <<= 1) s += __shfl_xor(s, d);
    const float inv = 1.f / s;
    float* op = out + ((size_t)b * N_ + n0 + r) * N_;
#pragma unroll
    for (int i = 0; i < 32; ++i) op[lane + (i << 6)] = a[i] * inv;
  }
}

extern "C" void kernel_launch(void* const* d_in, const int* in_sizes, int n_in,
                              void* d_out, int out_size, void* d_ws, size_t ws_size,
                              hipStream_t stream) {
  const float* x   = (const float*)d_in[0];
  const float* mem = (const float*)d_in[1];
  const float* fcw = (const float*)d_in[2];
  const float* fcb = (const float*)d_in[3];
  float* out = (float*)d_out;
  unsigned short* xsH  = (unsigned short*)d_ws;             // 2 MB
  unsigned short* xsL  = xsH + (size_t)B_ * N_ * C_;        // 2 MB
  unsigned short* memT = xsL + (size_t)B_ * N_ * C_;        // 128 KB

  dim3 g1(N_ / 64, B_);
  prep_kernel<<<g1, 256, 0, stream>>>(x, mem, xsH, xsL, memT);
  dim3 g2(N_ / 8, B_);
  adj_kernel<<<g2, 512, 0, stream>>>(xsH, xsL, memT, fcw, fcb, out);
}

// Round 7
// 179.636 us; speedup vs baseline: 18.3627x; 1.0258x over previous
//
#include <hip/hip_runtime.h>
#include <hip/hip_bf16.h>
#include <cstdint>
#include <cstddef>

#define B_ 16
#define N_ 2048
#define L_ 12
#define C_ 32
#define KTOP 1638
#define SCALE 0.17677669529663687f   // 1/sqrt(32)
#define LOG2E 1.44269504088896f

typedef __attribute__((ext_vector_type(8))) short short8v;
typedef __attribute__((ext_vector_type(4))) float f32x4;

#if __has_builtin(__builtin_amdgcn_exp2f)
#define EXP2F(x) __builtin_amdgcn_exp2f(x)
#else
#define EXP2F(x) exp2f(x)
#endif

__device__ __forceinline__ unsigned short bf16_rne(float v) {
  unsigned u = __float_as_uint(v);
  u += 0x7FFFu + ((u >> 16) & 1u);
  return (unsigned short)(u >> 16);
}

// Kernel 1: xsum split into bf16 hi/lo, layout [b][n][c]; blocks with b==0
// also convert mem (f32 [c][m]) -> bf16 memT [m][c] (batch-invariant).
__global__ __launch_bounds__(256) void prep_kernel(const float* __restrict__ x,
                                                   const float* __restrict__ mem,
                                                   unsigned short* __restrict__ xsH,
                                                   unsigned short* __restrict__ xsL,
                                                   unsigned short* __restrict__ memT) {
  const int b = blockIdx.y, n0 = blockIdx.x * 64;
  const int c = threadIdx.x & 31, nr = threadIdx.x >> 5;
#pragma unroll
  for (int i = 0; i < 8; ++i) {
    const int n = n0 + i * 8 + nr;
    const float* px = x + ((size_t)(b * N_ + n) * L_) * C_ + c;
    float s = 0.f;
#pragma unroll
    for (int l = 0; l < L_; ++l) s += px[l * C_];
    const unsigned short h = bf16_rne(s);
    const float hf = __uint_as_float((unsigned)h << 16);
    const unsigned short lo = bf16_rne(s - hf);
    const size_t o = (size_t)(b * N_ + n) * C_ + c;
    xsH[o] = h;
    xsL[o] = lo;
  }
  if (b == 0) {
#pragma unroll
    for (int i = 0; i < 8; ++i) {
      const int idx = i * 256 + threadIdx.x;
      const int ml = idx >> 5, cc = idx & 31;
      memT[(size_t)(n0 + ml) * C_ + cc] = bf16_rne(mem[(size_t)cc * N_ + n0 + ml]);
    }
  }
}

// Kernel 2: one block = 8 rows of one batch, 512 threads (8 waves).
// Phase A: MFMA 16x16x32 + max-free softmaxes, p1/p2 packed to pbuf.
// Phase B: cvt_pk adj reconstruct -> packed 15-bit keys -> SALU-free
// threshold search (packed-sub counting + shfl reduce) -> final softmax
// (no max subtract: |adj| <= 0.71).
__global__ __launch_bounds__(512, 4) void adj_kernel(
    const unsigned short* __restrict__ xsH, const unsigned short* __restrict__ xsL,
    const unsigned short* __restrict__ memT, const float* __restrict__ fc_w,
    const float* __restrict__ fc_b, float* __restrict__ out) {
  __shared__ unsigned pbuf[8][2049];      // +1 pad
  __shared__ float red1[8][8], red2[8][8];

  const int tid = threadIdx.x, wid = tid >> 6, lane = tid & 63;
  const int l15 = lane & 15, g = lane >> 4;
  const int b = blockIdx.y, n0 = blockIdx.x * 8;

  const size_t arow = (size_t)(b * N_ + n0 + (l15 & 7)) * C_ + g * 8;
  const short8v hiA = *(const short8v*)(xsH + arow);
  const short8v loA = *(const short8v*)(xsL + arow);

  const f32x4 zero = {0.f, 0.f, 0.f, 0.f};
  float s1[2] = {0.f, 0.f}, s2[2] = {0.f, 0.f};
  const float K = SCALE * LOG2E;
  const float C2 = -80.f * LOG2E;
  const size_t xbase = (size_t)b * N_ * C_;
  const int g8 = g * 8;
  const bool hih = (g & 2) != 0;
  const int rbase = (g & 1) * 4 + (g & 2);
  unsigned* pw = &pbuf[0][0] + rbase * 2049;

#pragma unroll 2
  for (int t = 0; t < 16; ++t) {
    const int m = wid * 256 + t * 16 + l15;
    const size_t brow = xbase + (size_t)m * C_ + g8;
    const short8v hiB = *(const short8v*)(xsH + brow);
    const short8v loB = *(const short8v*)(xsL + brow);
    const short8v mB  = *(const short8v*)(memT + (size_t)m * C_ + g8);

    f32x4 acc1 = __builtin_amdgcn_mfma_f32_16x16x32_bf16(hiA, mB, zero, 0, 0, 0);
    f32x4 acc2 = __builtin_amdgcn_mfma_f32_16x16x32_bf16(hiA, hiB, zero, 0, 0, 0);
    acc2 = __builtin_amdgcn_mfma_f32_16x16x32_bf16(hiA, loB, acc2, 0, 0, 0);
    acc2 = __builtin_amdgcn_mfma_f32_16x16x32_bf16(loA, hiB, acc2, 0, 0, 0);

#pragma unroll
    for (int s = 0; s < 2; ++s) {
      const float a1v = hih ? acc1[2 + s] : acc1[s];
      const float a2v = hih ? acc2[2 + s] : acc2[s];
      const float p1 = EXP2F(fmaxf(a1v, 0.f) * K);
      const float p2 = EXP2F(fminf(fmaf(fmaxf(a2v, 0.f), K, C2), 127.f));
      s1[s] += p1;
      s2[s] += p2;
      union { __hip_bfloat162 h2; unsigned u; } pk;
      pk.h2 = __float22bfloat162_rn(float2{p1, p2});
      pw[s * 2049 + m] = pk.u;
    }
  }

#pragma unroll
  for (int d = 1; d < 16; d <<= 1) {
#pragma unroll
    for (int s = 0; s < 2; ++s) {
      s1[s] += __shfl_xor(s1[s], d);
      s2[s] += __shfl_xor(s2[s], d);
    }
  }
  if (l15 == 0) {
#pragma unroll
    for (int s = 0; s < 2; ++s) {
      red1[wid][rbase + s] = s1[s];
      red2[wid][rbase + s] = s2[s];
    }
  }
  __syncthreads();

  // ---- Phase B: wave wid owns row wid ----
  {
    const int r = wid;
    float S1 = 0.f, S2 = 0.f;
#pragma unroll
    for (int w = 0; w < 8; ++w) { S1 += red1[w][r]; S2 += red2[w][r]; }
    const float w0 = fc_w[0], w1 = fc_w[1], bb = fc_b[0];
    const float i1 = w0 / S1, i2 = w1 / S2;
    const unsigned* prow = &pbuf[0][0] + r * 2049;

    unsigned pk[16];   // packed bf16 adj: lo half = col(lane+2j*64), hi = col(lane+(2j+1)*64)
    unsigned kg[16];   // guarded packed 15-bit sortable keys
    unsigned mnv = 0x7FFFu, mxv = 0u;
#pragma unroll
    for (int j = 0; j < 16; ++j) {
      const unsigned qa = prow[lane + (2 * j) * 64];
      const unsigned qb = prow[lane + (2 * j + 1) * 64];
      const float adjA = fmaf(__uint_as_float(qa & 0xFFFF0000u), i2,
                        fmaf(__uint_as_float(qa << 16), i1, bb));
      const float adjB = fmaf(__uint_as_float(qb & 0xFFFF0000u), i2,
                        fmaf(__uint_as_float(qb << 16), i1, bb));
      union { __hip_bfloat162 h2; unsigned u; } c;
      c.h2 = __float22bfloat162_rn(float2{adjA, adjB});
      pk[j] = c.u;
      const unsigned sgn = (c.u >> 15) & 0x00010001u;
      const unsigned srt = c.u ^ 0x80008000u ^ (sgn * 0x7FFFu);
      const unsigned k15 = (srt >> 1) & 0x7FFF7FFFu;
      kg[j] = k15 | 0x80008000u;
      mnv = min(mnv, min(k15 & 0xFFFFu, k15 >> 16));
      mxv = max(mxv, max(k15 & 0xFFFFu, k15 >> 16));
    }
#pragma unroll
    for (int d = 1; d < 64; d <<= 1) {
      mnv = min(mnv, (unsigned)__shfl_xor((int)mnv, d));
      mxv = max(mxv, (unsigned)__shfl_xor((int)mxv, d));
    }

    unsigned lo = mnv, hi = mxv;
#pragma unroll 1
    for (int it = 0; it < 15; ++it) {
      if (lo >= hi) break;
      const unsigned mid = (lo + hi + 1u) >> 1;
      const unsigned mm = mid | (mid << 16);
      unsigned c0 = 0, c1 = 0;
#pragma unroll
      for (int j = 0; j < 8; ++j) {
        c0 += ((kg[j] - mm) >> 15) & 0x00010001u;
        c1 += ((kg[8 + j] - mm) >> 15) & 0x00010001u;
      }
      unsigned cnt = c0 + c1;
      cnt = (cnt & 0xFFFFu) + (cnt >> 16);
#pragma unroll
      for (int d = 1; d < 64; d <<= 1) cnt += (unsigned)__shfl_xor((int)cnt, d);
      if (cnt >= KTOP) lo = mid; else hi = mid - 1;
    }

    const unsigned lolo = lo | (lo << 16);
    float ex[32];
    float s = 0.f;
#pragma unroll
    for (int j = 0; j < 16; ++j) {
      const unsigned ge = kg[j] - lolo;   // bit15: lo-half >= lo, bit31: hi-half >= lo
      const float vA = __uint_as_float(pk[j] << 16);
      const float vB = __uint_as_float(pk[j] & 0xFFFF0000u);
      float eA = EXP2F(vA * LOG2E);
      float eB = EXP2F(vB * LOG2E);
      eA = (ge & 0x8000u) ? eA : 1.0f;
      eB = (ge & 0x80000000u) ? eB : 1.0f;
      ex[2 * j] = eA; ex[2 * j + 1] = eB;
      s += eA + eB;
    }
#pragma unroll
    for (int d = 1; d < 64; d <<= 1) s += __shfl_xor(s, d);
    const float inv = 1.f / s;
    float* op = out + ((size_t)b * N_ + n0 + r) * N_;
#pragma unroll
    for (int j = 0; j < 32; ++j) op[lane + (j << 6)] = ex[j] * inv;
  }
}

extern "C" void kernel_launch(void* const* d_in, const int* in_sizes, int n_in,
                              void* d_out, int out_size, void* d_ws, size_t ws_size,
                              hipStream_t stream) {
  const float* x   = (const float*)d_in[0];
  const float* mem = (const float*)d_in[1];
  const float* fcw = (const float*)d_in[2];
  const float* fcb = (const float*)d_in[3];
  float* out = (float*)d_out;
  unsigned short* xsH  = (unsigned short*)d_ws;             // 2 MB
  unsigned short* xsL  = xsH + (size_t)B_ * N_ * C_;        // 2 MB
  unsigned short* memT = xsL + (size_t)B_ * N_ * C_;        // 128 KB

  dim3 g1(N_ / 64, B_);
  prep_kernel<<<g1, 256, 0, stream>>>(x, mem, xsH, xsL, memT);
  dim3 g2(N_ / 8, B_);
  adj_kernel<<<g2, 512, 0, stream>>>(xsH, xsL, memT, fcw, fcb, out);
}

// Round 8
// 146.576 us; speedup vs baseline: 22.5044x; 1.2256x over previous
//
#include <hip/hip_runtime.h>
#include <hip/hip_bf16.h>
#include <cstdint>
#include <cstddef>

#define B_ 16
#define N_ 2048
#define L_ 12
#define C_ 32
#define KTOP 1638
#define SCALE 0.17677669529663687f   // 1/sqrt(32)
#define LOG2E 1.44269504088896f

typedef __attribute__((ext_vector_type(8))) short short8v;
typedef __attribute__((ext_vector_type(4))) float f32x4;

#if __has_builtin(__builtin_amdgcn_exp2f)
#define EXP2F(x) __builtin_amdgcn_exp2f(x)
#else
#define EXP2F(x) exp2f(x)
#endif

__device__ __forceinline__ unsigned short bf16_rne(float v) {
  unsigned u = __float_as_uint(v);
  u += 0x7FFFu + ((u >> 16) & 1u);
  return (unsigned short)(u >> 16);
}

// Kernel 1: xsum split into bf16 hi/lo, layout [b][n][c]; blocks with b==0
// also convert mem (f32 [c][m]) -> bf16 memT [m][c] (batch-invariant).
__global__ __launch_bounds__(256) void prep_kernel(const float* __restrict__ x,
                                                   const float* __restrict__ mem,
                                                   unsigned short* __restrict__ xsH,
                                                   unsigned short* __restrict__ xsL,
                                                   unsigned short* __restrict__ memT) {
  const int b = blockIdx.y, n0 = blockIdx.x * 64;
  const int c = threadIdx.x & 31, nr = threadIdx.x >> 5;
#pragma unroll
  for (int i = 0; i < 8; ++i) {
    const int n = n0 + i * 8 + nr;
    const float* px = x + ((size_t)(b * N_ + n) * L_) * C_ + c;
    float s = 0.f;
#pragma unroll
    for (int l = 0; l < L_; ++l) s += px[l * C_];
    const unsigned short h = bf16_rne(s);
    const float hf = __uint_as_float((unsigned)h << 16);
    const unsigned short lo = bf16_rne(s - hf);
    const size_t o = (size_t)(b * N_ + n) * C_ + c;
    xsH[o] = h;
    xsL[o] = lo;
  }
  if (b == 0) {
#pragma unroll
    for (int i = 0; i < 8; ++i) {
      const int idx = i * 256 + threadIdx.x;
      const int ml = idx >> 5, cc = idx & 31;
      memT[(size_t)(n0 + ml) * C_ + cc] = bf16_rne(mem[(size_t)cc * N_ + n0 + ml]);
    }
  }
}

// Kernel 2: one block = 8 rows of one batch, 512 threads (8 waves).
// Phase A: MFMA 16x16x32 with PERMUTED A-row padding so each lane statically
// uses acc components {0,1} (no cndmask). Max-free softmaxes; p1/p2 packed.
// Phase B: reconstruct -> packed 15-bit keys -> tie-anchored fast-path
// top-k threshold (1 count for most rows; tightened search otherwise) ->
// final softmax (no max subtract: |adj| <= 0.71).
__global__ __launch_bounds__(512, 4) void adj_kernel(
    const unsigned short* __restrict__ xsH, const unsigned short* __restrict__ xsL,
    const unsigned short* __restrict__ memT, const float* __restrict__ fc_w,
    const float* __restrict__ fc_b, float* __restrict__ out) {
  __shared__ unsigned pbuf[8][2049];      // +1 pad
  __shared__ float red1[8][8], red2[8][8];

  const int tid = threadIdx.x, wid = tid >> 6, lane = tid & 63;
  const int l15 = lane & 15, g = lane >> 4;
  const int b = blockIdx.y, n0 = blockIdx.x * 8;

  // Permuted A rows: phys rows 8..15 hold logical (p-6)&7 -> lane group g's
  // C components {0,1} are exactly its assigned logical rows {rbase, rbase+1}.
  const int fr = (l15 < 8) ? l15 : ((l15 - 6) & 7);
  const size_t arow = (size_t)(b * N_ + n0 + fr) * C_ + g * 8;
  const short8v hiA = *(const short8v*)(xsH + arow);
  const short8v loA = *(const short8v*)(xsL + arow);

  const f32x4 zero = {0.f, 0.f, 0.f, 0.f};
  float s1[2] = {0.f, 0.f}, s2[2] = {0.f, 0.f};
  const float K = SCALE * LOG2E;
  const float C2 = -80.f * LOG2E;
  const int g8 = g * 8;
  const int rbase = (g & 1) * 4 + (g & 2);   // {0,4,2,6}
  const int mbase = wid * 256 + l15;
  const size_t bcol = (size_t)b * N_ * C_ + (size_t)mbase * C_ + g8;
  const unsigned short* pH = xsH + bcol;
  const unsigned short* pL = xsL + bcol;
  const unsigned short* pM = memT + (size_t)mbase * C_ + g8;
  unsigned* pw = &pbuf[rbase][mbase];

#pragma unroll
  for (int t = 0; t < 16; ++t) {
    const short8v hiB = *(const short8v*)(pH + t * (16 * C_));
    const short8v loB = *(const short8v*)(pL + t * (16 * C_));
    const short8v mB  = *(const short8v*)(pM + t * (16 * C_));

    f32x4 acc1 = __builtin_amdgcn_mfma_f32_16x16x32_bf16(hiA, mB, zero, 0, 0, 0);
    f32x4 acc2 = __builtin_amdgcn_mfma_f32_16x16x32_bf16(hiA, hiB, zero, 0, 0, 0);
    acc2 = __builtin_amdgcn_mfma_f32_16x16x32_bf16(hiA, loB, acc2, 0, 0, 0);
    acc2 = __builtin_amdgcn_mfma_f32_16x16x32_bf16(loA, hiB, acc2, 0, 0, 0);

#pragma unroll
    for (int s = 0; s < 2; ++s) {
      const float p1 = EXP2F(fmaxf(acc1[s], 0.f) * K);
      const float p2 = EXP2F(fminf(fmaf(fmaxf(acc2[s], 0.f), K, C2), 127.f));
      s1[s] += p1;
      s2[s] += p2;
      union { __hip_bfloat162 h2; unsigned u; } pk;
      pk.h2 = __float22bfloat162_rn(float2{p1, p2});
      pw[s * 2049 + t * 16] = pk.u;
    }
  }

#pragma unroll
  for (int d = 1; d < 16; d <<= 1) {
#pragma unroll
    for (int s = 0; s < 2; ++s) {
      s1[s] += __shfl_xor(s1[s], d);
      s2[s] += __shfl_xor(s2[s], d);
    }
  }
  if (l15 == 0) {
#pragma unroll
    for (int s = 0; s < 2; ++s) {
      red1[wid][rbase + s] = s1[s];
      red2[wid][rbase + s] = s2[s];
    }
  }
  __syncthreads();

  // ---- Phase B: wave wid owns row wid ----
  {
    const int r = wid;
    float S1 = 0.f, S2 = 0.f;
#pragma unroll
    for (int w = 0; w < 8; ++w) { S1 += red1[w][r]; S2 += red2[w][r]; }
    const float w0 = fc_w[0], w1 = fc_w[1], bb = fc_b[0];
    const float i1 = w0 / S1, i2 = w1 / S2;
    const unsigned* prow = &pbuf[0][0] + r * 2049;

    unsigned pk[16];   // packed bf16 adj pair per reg
    unsigned kg[16];   // guarded packed 15-bit sortable keys
#pragma unroll
    for (int j = 0; j < 16; ++j) {
      const unsigned qa = prow[lane + (2 * j) * 64];
      const unsigned qb = prow[lane + (2 * j + 1) * 64];
      const float adjA = fmaf(__uint_as_float(qa & 0xFFFF0000u), i2,
                        fmaf(__uint_as_float(qa << 16), i1, bb));
      const float adjB = fmaf(__uint_as_float(qb & 0xFFFF0000u), i2,
                        fmaf(__uint_as_float(qb << 16), i1, bb));
      union { __hip_bfloat162 h2; unsigned u; } c;
      c.h2 = __float22bfloat162_rn(float2{adjA, adjB});
      pk[j] = c.u;
      const unsigned sgn = (c.u >> 15) & 0x00010001u;
      const unsigned srt = c.u ^ 0x80008000u ^ (sgn * 0x7FFFu);
      kg[j] = ((srt >> 1) & 0x7FFF7FFFu) | 0x80008000u;
    }

    // Tie-anchor: T = adj value of the all-relu-zero class, reproduced with
    // phase A's exact arithmetic. Fast path is self-verifying via counts.
    const float p2t = __uint_as_float((unsigned)bf16_rne(EXP2F(C2)) << 16);
    const float Tval = fmaf(p2t, i2, fmaf(1.0f, i1, bb));
    const unsigned short bT = bf16_rne(Tval);
    const unsigned sT = bT >> 15;
    const unsigned kT = ((((unsigned)bT ^ 0x8000u ^ (sT * 0x7FFFu)) >> 1) & 0x7FFFu);

    const unsigned mmA = kT * 0x10001u;
    const unsigned mmB = (kT + 1u) * 0x10001u;
    unsigned cAp = 0, cBp = 0;
#pragma unroll
    for (int j = 0; j < 16; ++j) {
      cAp += ((kg[j] - mmA) >> 15) & 0x10001u;
      cBp += ((kg[j] - mmB) >> 15) & 0x10001u;
    }
    unsigned comb = ((cAp & 0xFFFFu) + (cAp >> 16)) |
                    (((cBp & 0xFFFFu) + (cBp >> 16)) << 16);
#pragma unroll
    for (int d = 1; d < 64; d <<= 1) comb += (unsigned)__shfl_xor((int)comb, d);
    const unsigned cge = comb & 0xFFFFu, cgt = comb >> 16;

    unsigned lo;
    if (cge >= KTOP && cgt < KTOP) {
      lo = kT;                                   // exact search result, proven by counts
    } else {
      unsigned mnv = 0xFFFFu, mxv = 0u;
#pragma unroll
      for (int j = 0; j < 16; ++j) {
        const unsigned k15 = kg[j] & 0x7FFF7FFFu;
        mnv = min(mnv, min(k15 & 0xFFFFu, k15 >> 16));
        mxv = max(mxv, max(k15 & 0xFFFFu, k15 >> 16));
      }
#pragma unroll
      for (int d = 1; d < 64; d <<= 1) {
        mnv = min(mnv, (unsigned)__shfl_xor((int)mnv, d));
        mxv = max(mxv, (unsigned)__shfl_xor((int)mxv, d));
      }
      unsigned hi;
      if (cge < KTOP) { lo = mnv; hi = kT - 1u; }   // answer < kT
      else            { lo = kT + 1u; hi = mxv; }   // answer > kT (cnt_ge(kT+1)>=KTOP)
#pragma unroll 1
      for (int it = 0; it < 15; ++it) {
        if (lo >= hi) break;
        const unsigned mid = (lo + hi + 1u) >> 1;
        const unsigned mm = mid * 0x10001u;
        unsigned c0 = 0;
#pragma unroll
        for (int j = 0; j < 16; ++j) c0 += ((kg[j] - mm) >> 15) & 0x10001u;
        unsigned cnt = (c0 & 0xFFFFu) + (c0 >> 16);
#pragma unroll
        for (int d = 1; d < 64; d <<= 1) cnt += (unsigned)__shfl_xor((int)cnt, d);
        if (cnt >= KTOP) lo = mid; else hi = mid - 1u;
      }
    }

    const unsigned lolo = lo * 0x10001u;
    float ex[32];
    float s = 0.f;
#pragma unroll
    for (int j = 0; j < 16; ++j) {
      const unsigned ge = kg[j] - lolo;   // bit15: lo-half kept, bit31: hi-half kept
      float eA = EXP2F(__uint_as_float(pk[j] << 16) * LOG2E);
      float eB = EXP2F(__uint_as_float(pk[j] & 0xFFFF0000u) * LOG2E);
      eA = (ge & 0x8000u) ? eA : 1.0f;
      eB = (ge & 0x80000000u) ? eB : 1.0f;
      ex[2 * j] = eA; ex[2 * j + 1] = eB;
      s += eA + eB;
    }
#pragma unroll
    for (int d = 1; d < 64; d <<= 1) s += __shfl_xor(s, d);
    const float inv = 1.f / s;
    float* op = out + ((size_t)b * N_ + n0 + r) * N_;
#pragma unroll
    for (int j = 0; j < 32; ++j) op[lane + (j << 6)] = ex[j] * inv;
  }
}

extern "C" void kernel_launch(void* const* d_in, const int* in_sizes, int n_in,
                              void* d_out, int out_size, void* d_ws, size_t ws_size,
                              hipStream_t stream) {
  const float* x   = (const float*)d_in[0];
  const float* mem = (const float*)d_in[1];
  const float* fcw = (const float*)d_in[2];
  const float* fcb = (const float*)d_in[3];
  float* out = (float*)d_out;
  unsigned short* xsH  = (unsigned short*)d_ws;             // 2 MB
  unsigned short* xsL  = xsH + (size_t)B_ * N_ * C_;        // 2 MB
  unsigned short* memT = xsL + (size_t)B_ * N_ * C_;        // 128 KB

  dim3 g1(N_ / 64, B_);
  prep_kernel<<<g1, 256, 0, stream>>>(x, mem, xsH, xsL, memT);
  dim3 g2(N_ / 8, B_);
  adj_kernel<<<g2, 512, 0, stream>>>(xsH, xsL, memT, fcw, fcb, out);
}